// Round 7
// baseline (677.495 us; speedup 1.0000x reference)
//
#include <hip/hip_runtime.h>

typedef float f2 __attribute__((ext_vector_type(2)));

#define DIM   256
#define RANK  64
#define NSEG0 192                 // dim - rank = shortest segment
#define N0    14304               // sum_{j=0}^{63} (192+j) complex pairs per batch
#define NW    8                   // waves per block (scan bands of 8)
#define TILE  16                  // rows per staged trig tile

// Complex Givens-with-phase rotation, written for VOP3P (v_pk_fma_f32)
// selection: all math on <2 x float>, negations inside fma sources (fold to
// neg_lo/neg_hi), splats as {s,s} (fold to op_sel), act-select as whole-vector
// ternary. Ideal codegen: 8 v_pk ops + 2 v_cndmask per rotation.
__device__ __forceinline__ void rot(const float4 q, f2& V, f2& Acc, bool act)
{
    const f2 ct2 = {q.x, q.x};
    const f2 st2 = {q.y, q.y};
    const f2 er2 = {q.z, q.z};
    const f2 ei2 = {q.w, q.w};
    const f2 u   = __builtin_elementwise_fma(-st2, V,   ct2 * Acc); // ct*a - st*v
    const f2 pp  = __builtin_elementwise_fma( st2, Acc, ct2 * V);   // ct*v + st*a
    const f2 usn = {u.y, -u.x};
    const f2 psn = {-pp.y, pp.x};
    const f2 z   = __builtin_elementwise_fma(ei2, usn, er2 * u);    // u * conj(e)
    Acc          = __builtin_elementwise_fma(ei2, psn, er2 * pp);   // pp * e
    V = act ? z : V;
}

// Wavefront-pipelined fused formulation (R6 structure, NW=8, 8 waves/SIMD).
// Output convention (proven R1-R3): d_out = REAL part, (batch,256,64) fp32.
__global__ __launch_bounds__(64 * NW, NW)
void stiefel_pipe(const float* __restrict__ theta, float* __restrict__ out,
                  long long out_limit)
{
    const int b   = blockIdx.x;
    const int tid = threadIdx.x;
    const int w   = tid >> 6;                        // scan band 0..7
    const int c   = tid & 63;                        // column lane

    const float2* tb = (const float2*)theta + (size_t)b * N0;   // (t,p) pairs
    const long long obase = (long long)b * (DIM * RANK);

    __shared__ float4 trigT[2][TILE][64];            // [parity][row][seg]  32 KB
    __shared__ float2 pipe[NW - 1][2][64];           // [boundary][row parity][col]

    const int jbase = 8 * w;
    const int cthr  = 64 - jbase;                    // act: c + k >= cthr

    f2 A[8];                                         // carries for scans jbase+k
    #pragma unroll
    for (int k = 0; k < 8; ++k) A[k] = (f2){0.f, 0.f};

    // staging: thread tid owns segment jS, rows rS..rS+1 of each 16-row tile
    const int jS   = tid & 63;
    const int rS   = (tid >> 6) << 1;                // 0,2,..,14
    const int offS = NSEG0 * jS + ((jS * (jS - 1)) >> 1);
    const int lenS = NSEG0 + jS;

    // rowJ generator state (wave 0; lane c <-> segment 63-c)
    const int len0 = NSEG0 + 63 - c;                 // = 255-c
    float S = 1.f, Er = 1.f, Ei = 0.f;

    // all band scans are pure rotations while i < fastlim
    const int fastlim = NSEG0 + ((w == 0) ? 0 : jbase);

    #pragma unroll 1
    for (int s = 0; s < DIM + NW - 1; ++s) {
        // ---- stage trig tile (cos t, sin t, cos p, sin p) ----
        if ((s & (TILE - 1)) == 0 && s < DIM) {
            const int pS = (s >> 4) & 1;
            #pragma unroll
            for (int u = 0; u < 2; ++u) {
                const int i = s + rS + u;
                if (i < lenS) {
                    const float2 tp = tb[offS + i];
                    trigT[pS][rS + u][jS] =
                        make_float4(__cosf(tp.x), __sinf(tp.x),
                                    __cosf(tp.y), __sinf(tp.y));
                }
            }
        }
        __syncthreads();                             // the step boundary

        const int i = s - w;                         // this band's row this step
        if (i >= 0 && i < DIM) {
            const int p  = (i >> 4) & 1;
            const int ti = i & (TILE - 1);

            // ---- value entering this band ----
            f2 V;
            if (w == 0) {                            // generate rowJ value
                if (i < len0) {
                    const float4 q = trigT[p][ti][63 - c];
                    const float Fr = Er * q.z + Ei * q.w;   // E * conj(e_i)
                    const float Fi = Ei * q.z - Er * q.w;
                    const float amp = q.x * S;              // ct_i * prod st
                    V = (f2){amp * Fr, amp * Fi};
                    S *= q.y;
                    const float nEr = Er * q.z - Ei * q.w;  // E *= e_i
                    const float nEi = Ei * q.z + Er * q.w;
                    Er = nEr; Ei = nEi;
                } else if (i == len0) { V = (f2){S * Er, S * Ei}; }
                else                  { V = (f2){0.f, 0.f}; }
            } else {
                const float2 vin = pipe[w - 1][i & 1][c];
                V = (f2){vin.x, vin.y};
            }

            const float4* tq = &trigT[p][ti][jbase]; // tq[k]: broadcast reads
            if (i < fastlim) {
                // straight-line: 8 rotations, no deposits
                #pragma unroll
                for (int k = 0; k < 8; ++k)
                    rot(tq[k], V, A[k], c + k >= cthr);
            } else {
                // tail rows: mixed rotate / deposit / dead per k (wave-uniform i)
                #pragma unroll
                for (int k = 0; k < 8; ++k) {
                    const int j = jbase + k;
                    const int limit = NSEG0 + j;
                    if (i > limit) continue;
                    const bool act = (c + k >= cthr);
                    if (i == limit) {                // deposit scan j's carry
                        V = act ? A[k] : V;
                    } else {
                        rot(tq[k], V, A[k], act);
                    }
                }
            }

            // ---- pass v to next band / emit real part ----
            if (w < NW - 1) {
                pipe[w][i & 1][c] = make_float2(V.x, V.y);
            } else {
                const long long oidx = obase + (long long)i * RANK + c;
                if (oidx < out_limit) out[oidx] = V.x;
            }
        }
    }
}

extern "C" void kernel_launch(void* const* d_in, const int* in_sizes, int n_in,
                              void* d_out, int out_size, void* d_ws, size_t ws_size,
                              hipStream_t stream)
{
    const float* theta = (const float*)d_in[0];
    float* out = (float*)d_out;
    const int batch = in_sizes[0] / (2 * N0);        // 1024 for this problem
    if (batch <= 0) return;

    stiefel_pipe<<<batch, 64 * NW, 0, stream>>>(theta, out, (long long)out_size);
}

// Round 8
// 572.310 us; speedup vs baseline: 1.1838x; 1.1838x over previous
//
#include <hip/hip_runtime.h>

typedef float f2 __attribute__((ext_vector_type(2)));

#define DIM   256
#define RANK  64
#define NSEG0 192                 // dim - rank = shortest segment
#define N0    14304               // sum_{j=0}^{63} (192+j) complex pairs per batch
#define NW    8                   // waves per block (scan bands of 8)
#define TILE  16                  // rows per staged trig tile

// Complex Givens-with-phase rotation in hand-written VOP3P (R7 post-mortem:
// the compiler never forms v_pk_fma_f32 from source idioms; R6 scalar form
// was ~20 instr/rotation and the kernel is issue-count-bound at 8 waves/SIMD).
// 8 packed ops, all splats/swaps/signs folded into op_sel / neg modifiers:
//   u  = ct*A - st*V              (2 pk)
//   pp = ct*V + st*A              (2 pk)
//   z  = u * conj(e)  -> new V    (2 pk; swap via op_sel, sign via neg_hi)
//   A' = pp * e                   (2 pk; swap via op_sel, sign via neg_lo)
// qts = (cos t, sin t), qps = (cos p, sin p) as VGPR pairs.
__device__ __forceinline__ void rot_pk(const f2 qts, const f2 qps, f2& V, f2& A,
                                       bool act)
{
    f2 t1, u, t2, pp, t3, z, t4;
    // t1 = {ct,ct} * A
    asm("v_pk_mul_f32 %0, %1, %2 op_sel:[0,0] op_sel_hi:[0,1]"
        : "=v"(t1) : "v"(qts), "v"(A));
    // u = -{st,st} * V + t1
    asm("v_pk_fma_f32 %0, %1, %2, %3 op_sel:[1,0,0] op_sel_hi:[1,1,1] neg_lo:[1,0,0] neg_hi:[1,0,0]"
        : "=v"(u) : "v"(qts), "v"(V), "v"(t1));
    // t2 = {ct,ct} * V
    asm("v_pk_mul_f32 %0, %1, %2 op_sel:[0,0] op_sel_hi:[0,1]"
        : "=v"(t2) : "v"(qts), "v"(V));
    // pp = {st,st} * A + t2
    asm("v_pk_fma_f32 %0, %1, %2, %3 op_sel:[1,0,0] op_sel_hi:[1,1,1]"
        : "=v"(pp) : "v"(qts), "v"(A), "v"(t2));
    // t3 = {er,er} * u
    asm("v_pk_mul_f32 %0, %1, %2 op_sel:[0,0] op_sel_hi:[0,1]"
        : "=v"(t3) : "v"(qps), "v"(u));
    // z = {ei,ei} * {u.y, -u.x} + t3        (u * conj(e))
    asm("v_pk_fma_f32 %0, %1, %2, %3 op_sel:[1,1,0] op_sel_hi:[1,0,1] neg_hi:[0,1,0]"
        : "=v"(z) : "v"(qps), "v"(u), "v"(t3));
    // t4 = {er,er} * pp
    asm("v_pk_mul_f32 %0, %1, %2 op_sel:[0,0] op_sel_hi:[0,1]"
        : "=v"(t4) : "v"(qps), "v"(pp));
    // A = {ei,ei} * {-pp.y, pp.x} + t4      (pp * e)
    asm("v_pk_fma_f32 %0, %1, %2, %3 op_sel:[1,1,0] op_sel_hi:[1,0,1] neg_lo:[0,1,0]"
        : "=v"(A) : "v"(qps), "v"(pp), "v"(t4));
    // act is row-invariant per (lane,k): v_cmp hoists; 2 cndmask remain
    V.x = act ? z.x : V.x;
    V.y = act ? z.y : V.y;
}

// Wavefront-pipelined fused formulation (R6 structure, NW=8, 8 waves/SIMD).
// Output convention (proven R1-R3): d_out = REAL part, (batch,256,64) fp32.
__global__ __launch_bounds__(64 * NW, NW)
void stiefel_pipe(const float* __restrict__ theta, float* __restrict__ out,
                  long long out_limit)
{
    const int b   = blockIdx.x;
    const int tid = threadIdx.x;
    const int w   = tid >> 6;                        // scan band 0..7
    const int c   = tid & 63;                        // column lane

    const float2* tb = (const float2*)theta + (size_t)b * N0;   // (t,p) pairs
    const long long obase = (long long)b * (DIM * RANK);

    __shared__ float4 trigT[2][TILE][64];            // [parity][row][seg]  32 KB
    __shared__ float2 pipe[NW - 1][2][64];           // [boundary][row parity][col]

    const int jbase = 8 * w;
    const int cthr  = 64 - jbase;                    // act: c + k >= cthr

    f2 A[8];                                         // carries for scans jbase+k
    #pragma unroll
    for (int k = 0; k < 8; ++k) A[k] = (f2){0.f, 0.f};

    // staging: thread tid owns segment jS, rows rS..rS+1 of each 16-row tile
    const int jS   = tid & 63;
    const int rS   = (tid >> 6) << 1;                // 0,2,..,14
    const int offS = NSEG0 * jS + ((jS * (jS - 1)) >> 1);
    const int lenS = NSEG0 + jS;

    // rowJ generator state (wave 0; lane c <-> segment 63-c)
    const int len0 = NSEG0 + 63 - c;                 // = 255-c
    float S = 1.f, Er = 1.f, Ei = 0.f;

    // all band scans are pure rotations while i < fastlim
    const int fastlim = NSEG0 + ((w == 0) ? 0 : jbase);

    #pragma unroll 1
    for (int s = 0; s < DIM + NW - 1; ++s) {
        // ---- stage trig tile (cos t, sin t, cos p, sin p) ----
        if ((s & (TILE - 1)) == 0 && s < DIM) {
            const int pS = (s >> 4) & 1;
            #pragma unroll
            for (int u = 0; u < 2; ++u) {
                const int i = s + rS + u;
                if (i < lenS) {
                    const float2 tp = tb[offS + i];
                    trigT[pS][rS + u][jS] =
                        make_float4(__cosf(tp.x), __sinf(tp.x),
                                    __cosf(tp.y), __sinf(tp.y));
                }
            }
        }
        __syncthreads();                             // the step boundary

        const int i = s - w;                         // this band's row this step
        if (i >= 0 && i < DIM) {
            const int p  = (i >> 4) & 1;
            const int ti = i & (TILE - 1);

            // ---- value entering this band ----
            f2 V;
            if (w == 0) {                            // generate rowJ value
                if (i < len0) {
                    const float4 q = trigT[p][ti][63 - c];
                    const float Fr = Er * q.z + Ei * q.w;   // E * conj(e_i)
                    const float Fi = Ei * q.z - Er * q.w;
                    const float amp = q.x * S;              // ct_i * prod st
                    V = (f2){amp * Fr, amp * Fi};
                    S *= q.y;
                    const float nEr = Er * q.z - Ei * q.w;  // E *= e_i
                    const float nEi = Ei * q.z + Er * q.w;
                    Er = nEr; Ei = nEi;
                } else if (i == len0) { V = (f2){S * Er, S * Ei}; }
                else                  { V = (f2){0.f, 0.f}; }
            } else {
                const float2 vin = pipe[w - 1][i & 1][c];
                V = (f2){vin.x, vin.y};
            }

            const float4* tq = &trigT[p][ti][jbase]; // tq[k]: broadcast reads
            if (i < fastlim) {
                // straight-line: 8 rotations, no deposits
                #pragma unroll
                for (int k = 0; k < 8; ++k) {
                    const float4 q = tq[k];
                    const f2 qts = {q.x, q.y};
                    const f2 qps = {q.z, q.w};
                    rot_pk(qts, qps, V, A[k], c + k >= cthr);
                }
            } else {
                // tail rows: mixed rotate / deposit / dead per k (wave-uniform i)
                #pragma unroll
                for (int k = 0; k < 8; ++k) {
                    const int j = jbase + k;
                    const int limit = NSEG0 + j;
                    if (i > limit) continue;
                    const bool act = (c + k >= cthr);
                    if (i == limit) {                // deposit scan j's carry
                        V.x = act ? A[k].x : V.x;
                        V.y = act ? A[k].y : V.y;
                    } else {
                        const float4 q = tq[k];
                        const f2 qts = {q.x, q.y};
                        const f2 qps = {q.z, q.w};
                        rot_pk(qts, qps, V, A[k], act);
                    }
                }
            }

            // ---- pass v to next band / emit real part ----
            if (w < NW - 1) {
                pipe[w][i & 1][c] = make_float2(V.x, V.y);
            } else {
                const long long oidx = obase + (long long)i * RANK + c;
                if (oidx < out_limit) out[oidx] = V.x;
            }
        }
    }
}

extern "C" void kernel_launch(void* const* d_in, const int* in_sizes, int n_in,
                              void* d_out, int out_size, void* d_ws, size_t ws_size,
                              hipStream_t stream)
{
    const float* theta = (const float*)d_in[0];
    float* out = (float*)d_out;
    const int batch = in_sizes[0] / (2 * N0);        // 1024 for this problem
    if (batch <= 0) return;

    stiefel_pipe<<<batch, 64 * NW, 0, stream>>>(theta, out, (long long)out_size);
}